// Round 5
// baseline (3572.036 us; speedup 1.0000x reference)
//
#include <hip/hip_runtime.h>
#include <hip/hip_bf16.h>

// LSTM forward: T=512 (511 steps), B=1024, I=128, H=256, 4H=1024.
// Round 5: epoch-stamped publish — h values carried as u32 granules
// [epoch(hi16) | bf16(lo16)] through relaxed agent-scope atomics. Consumers
// poll the data itself (no flags, no store drain, no release/acquire fences).
// 256 wgs = 64 batch groups x 4 hidden slices; W_hh LDS-resident, W_ih in
// registers; x-part GEMM runs in the sync shadow.

#define T_STEPS 511
#define BATCH   1024
#define IN      128
#define HID     256
#define NG      1024
#define KTOT    384
#define BWG     16
#define NGROUP  64
#define SW      264   // LDS W_hh row stride (bf16)
#define HS      264   // LDS Ah row stride (bf16)

typedef __bf16 bf16x8 __attribute__((ext_vector_type(8)));
typedef float  f32x4  __attribute__((ext_vector_type(4)));
typedef unsigned long long u64;
typedef unsigned int u32;
typedef u32 u32x4 __attribute__((ext_vector_type(4)));

// workspace layout (bytes)
#define WCAT_OFF 0
#define BIAS_OFF 786432
#define HEXG_OFF 790528                 // 2*64*16*256 u32 = 8 MB

__global__ void precast_kernel(const float* __restrict__ W_ih,
                               const float* __restrict__ W_hh,
                               const float* __restrict__ b_ih,
                               const float* __restrict__ b_hh,
                               __bf16* __restrict__ wcat,
                               float* __restrict__ bias) {
    int idx = blockIdx.x * blockDim.x + threadIdx.x;
    if (idx < NG * KTOT) {
        int n = idx / KTOT, k = idx % KTOT;
        float v = (k < IN) ? W_ih[n * IN + k] : W_hh[n * HID + (k - IN)];
        wcat[idx] = (__bf16)v;
    }
    if (idx < NG) bias[idx] = b_ih[idx] + b_hh[idx];
}

__device__ __forceinline__ float sigmoidf_fast(float v) {
    return 1.f / (1.f + __expf(-v));
}
__device__ __forceinline__ float tanhf_fast(float v) {
    return 1.f - 2.f / (1.f + __expf(2.f * v));
}

#define MFMA(a, b, c) __builtin_amdgcn_mfma_f32_16x16x32_bf16((a), (b), (c), 0, 0, 0)

__device__ __forceinline__ bf16x8 cvt_pack(float4 lo, float4 hi) {
    return bf16x8{(__bf16)lo.x, (__bf16)lo.y, (__bf16)lo.z, (__bf16)lo.w,
                  (__bf16)hi.x, (__bf16)hi.y, (__bf16)hi.z, (__bf16)hi.w};
}

__global__ __launch_bounds__(512, 2) void lstm_kernel(
    const float* __restrict__ x,      // (512,1024,128) fp32
    const __bf16* __restrict__ wcat,  // (1024,384) bf16
    const float* __restrict__ bias,   // (1024,)
    const float* __restrict__ hx0,
    const float* __restrict__ cx0,
    u32* __restrict__ hexg,           // [2][64][16][256] u32 (epoch|bf16)
    float* __restrict__ out)          // h (1024,256), c (1024,256) fp32
{
    __shared__ alignas(16) __bf16 Whh[256 * SW];   // 135168 B
    __shared__ alignas(16) __bf16 Ah[BWG * HS];    //   8448 B

    const int tid  = threadIdx.x;
    const int bx   = blockIdx.x;
    const int g    = bx & 63;          // batch group 0..63
    const int s    = bx >> 6;          // hidden slice 0..3
    const int wave = tid >> 6;
    const int lane = tid & 63;
    const int col  = lane & 15;
    const int quad = lane >> 4;
    const int hf   = col >> 3;         // 0: {i,g} lanes, 1: {f,o} lanes
    const int b0   = g * BWG;
    const int j0   = s * 64;
    const int jcol = j0 + wave * 8 + (col & 7);

    // ---- fill LDS W_hh ----
    {
        int r  = tid >> 1;
        int hh = (tid & 1) * 128;
        int ngl = ((r >> 6) << 8) + j0 + (r & 63);
        const __bf16* src = wcat + (size_t)ngl * KTOT + IN + hh;
        __bf16* dst = &Whh[r * SW + hh];
        #pragma unroll
        for (int i = 0; i < 16; ++i)
            *(bf16x8*)(dst + i * 8) = *(const bf16x8*)(src + i * 8);
    }

    // ---- W_ih fragments in registers: tile0 {i|f}, tile1 {g|o} ----
    const int n0 = (hf ? 256 : 0) + jcol;
    const int n1 = 512 + (hf ? 256 : 0) + jcol;
    bf16x8 wi0[4], wi1[4];
    #pragma unroll
    for (int ks = 0; ks < 4; ++ks) {
        wi0[ks] = *(const bf16x8*)(wcat + (size_t)n0 * KTOT + ks * 32 + quad * 8);
        wi1[ks] = *(const bf16x8*)(wcat + (size_t)n1 * KTOT + ks * 32 + quad * 8);
    }

    const float bi  = bias[jcol];
    const float bfv = bias[256 + jcol];
    const float bg  = bias[512 + jcol];
    const float bo  = bias[768 + jcol];

    float cst[4], hn[4];
    {
        float cv = cx0[jcol];
        #pragma unroll
        for (int r = 0; r < 4; ++r) cst[r] = cv;
    }

    // ---- x[0] and x[1] prefetch ----
    float4 x0f[8], xf[8];
    #pragma unroll
    for (int ks = 0; ks < 4; ++ks) {
        const float* xp = x + (size_t)(b0 + col) * IN + ks * 32 + quad * 8;
        x0f[2 * ks]     = *(const float4*)xp;
        x0f[2 * ks + 1] = *(const float4*)(xp + 4);
        const float* xq = xp + (size_t)BATCH * IN;
        xf[2 * ks]      = *(const float4*)xq;
        xf[2 * ks + 1]  = *(const float4*)(xq + 4);
    }

    const int nl0 = hf * 64 + wave * 8 + (col & 7);
    const __bf16* wl0 = &Whh[nl0 * SW + quad * 8];
    const __bf16* wl1 = &Whh[(128 + nl0) * SW + quad * 8];

    __syncthreads();   // Whh ready

    // ---- x-part for t=0 ----
    f32x4 aA0 = {0.f,0.f,0.f,0.f}, aA1 = {0.f,0.f,0.f,0.f};
    f32x4 aB0 = {0.f,0.f,0.f,0.f}, aB1 = {0.f,0.f,0.f,0.f};
    {
        bf16x8 ax[4];
        #pragma unroll
        for (int ks = 0; ks < 4; ++ks)
            ax[ks] = cvt_pack(x0f[2 * ks], x0f[2 * ks + 1]);
        aA0 = MFMA(ax[0], wi0[0], aA0); aB0 = MFMA(ax[0], wi1[0], aB0);
        aA1 = MFMA(ax[1], wi0[1], aA1); aB1 = MFMA(ax[1], wi1[1], aB1);
        aA0 = MFMA(ax[2], wi0[2], aA0); aB0 = MFMA(ax[2], wi1[2], aB0);
        aA1 = MFMA(ax[3], wi0[3], aA1); aB1 = MFMA(ax[3], wi1[3], aB1);
    }

    for (int t = 0; t < T_STEPS; ++t) {
        // ---- A: obtain h_t A-fragments ----
        bf16x8 ahf[8];
        if (t == 0) {
            #pragma unroll
            for (int ks = 0; ks < 8; ++ks) {
                const float* hp = hx0 + ks * 32 + quad * 8;
                ahf[ks] = cvt_pack(*(const float4*)hp, *(const float4*)(hp + 4));
            }
        } else {
            // poll own 32B of epoch-stamped h directly
            const u64* sp = (const u64*)hexg
                + ((size_t)((t & 1) * NGROUP + g)) * (BWG * HID / 2) + tid * 4;
            const u64 et = ((u64)(u32)t << 16) | ((u64)(u32)t << 48);
            u64 v0, v1, v2, v3;
            int guard = 0;
            for (;;) {
                v0 = __hip_atomic_load(sp + 0, __ATOMIC_RELAXED, __HIP_MEMORY_SCOPE_AGENT);
                v1 = __hip_atomic_load(sp + 1, __ATOMIC_RELAXED, __HIP_MEMORY_SCOPE_AGENT);
                v2 = __hip_atomic_load(sp + 2, __ATOMIC_RELAXED, __HIP_MEMORY_SCOPE_AGENT);
                v3 = __hip_atomic_load(sp + 3, __ATOMIC_RELAXED, __HIP_MEMORY_SCOPE_AGENT);
                u64 bad = ((v0 ^ et) | (v1 ^ et) | (v2 ^ et) | (v3 ^ et))
                        & 0xFFFF0000FFFF0000ull;
                if (bad == 0) break;
                if (++guard > (1 << 18)) break;   // fail-fast over deadlock
                __builtin_amdgcn_s_sleep(1);
            }
            // extract bf16 payloads -> LDS staging
            int row = tid >> 5, c8 = (tid & 31) * 8;
            u32x4 pk;
            pk.x = (u32)(v0 & 0xFFFF) | ((u32)((v0 >> 32) & 0xFFFF) << 16);
            pk.y = (u32)(v1 & 0xFFFF) | ((u32)((v1 >> 32) & 0xFFFF) << 16);
            pk.z = (u32)(v2 & 0xFFFF) | ((u32)((v2 >> 32) & 0xFFFF) << 16);
            pk.w = (u32)(v3 & 0xFFFF) | ((u32)((v3 >> 32) & 0xFFFF) << 16);
            *(u32x4*)&Ah[row * HS + c8] = pk;
            __syncthreads();
            #pragma unroll
            for (int ks = 0; ks < 8; ++ks)
                ahf[ks] = *(const bf16x8*)&Ah[col * HS + ks * 32 + quad * 8];
            __syncthreads();   // frags read; Ah may be overwritten next step
        }

        // ---- B: h-part MFMAs + cell ----
        #pragma unroll
        for (int ks = 0; ks < 4; ++ks) {
            bf16x8 w0a = *(const bf16x8*)(wl0 + ks * 32);
            bf16x8 w1a = *(const bf16x8*)(wl1 + ks * 32);
            bf16x8 w0b = *(const bf16x8*)(wl0 + (ks + 4) * 32);
            bf16x8 w1b = *(const bf16x8*)(wl1 + (ks + 4) * 32);
            aA0 = MFMA(ahf[ks],     w0a, aA0);
            aB0 = MFMA(ahf[ks],     w1a, aB0);
            aA1 = MFMA(ahf[ks + 4], w0b, aA1);
            aB1 = MFMA(ahf[ks + 4], w1b, aB1);
        }
        f32x4 accA = aA0 + aA1;   // i (hf=0) / f (hf=1)
        f32x4 accB = aB0 + aB1;   // g (hf=0) / o (hf=1)

        #pragma unroll
        for (int r = 0; r < 4; ++r) {
            float oA = __shfl_xor(accA[r], 8, 64);
            float oB = __shfl_xor(accB[r], 8, 64);
            float iv = (hf ? oA : accA[r]) + bi;
            float fv = (hf ? accA[r] : oA) + bfv;
            float gv = (hf ? oB : accB[r]) + bg;
            float ov = (hf ? accB[r] : oB) + bo;
            float ig = sigmoidf_fast(iv);
            float fg = sigmoidf_fast(fv);
            float gt = tanhf_fast(gv);
            float og = sigmoidf_fast(ov);
            float cn = fg * cst[r] + ig * gt;
            cst[r] = cn;
            hn[r]  = og * tanhf_fast(cn);
        }

        // ---- C: publish h_{t+1} as epoch-stamped u32 granules ----
        if (t < T_STEPS - 1) {
            if (col < 8) {
                u32* base = hexg
                    + ((size_t)(((t + 1) & 1) * NGROUP + g)) * (BWG * HID) + jcol;
                const u32 ep = ((u32)(t + 1)) << 16;
                #pragma unroll
                for (int r = 0; r < 4; ++r) {
                    __bf16 hv = (__bf16)hn[r];
                    unsigned short hb;
                    __builtin_memcpy(&hb, &hv, 2);
                    __hip_atomic_store(base + (quad * 4 + r) * HID, (u32)hb | ep,
                                       __ATOMIC_RELAXED, __HIP_MEMORY_SCOPE_AGENT);
                }
            }

            // ---- D: x-part for t+1 in the sync shadow ----
            {
                bf16x8 ax[4];
                #pragma unroll
                for (int ks = 0; ks < 4; ++ks)
                    ax[ks] = cvt_pack(xf[2 * ks], xf[2 * ks + 1]);
                aA0 = {0.f,0.f,0.f,0.f}; aA1 = {0.f,0.f,0.f,0.f};
                aB0 = {0.f,0.f,0.f,0.f}; aB1 = {0.f,0.f,0.f,0.f};
                aA0 = MFMA(ax[0], wi0[0], aA0); aB0 = MFMA(ax[0], wi1[0], aB0);
                aA1 = MFMA(ax[1], wi0[1], aA1); aB1 = MFMA(ax[1], wi1[1], aB1);
                aA0 = MFMA(ax[2], wi0[2], aA0); aB0 = MFMA(ax[2], wi1[2], aB0);
                aA1 = MFMA(ax[3], wi0[3], aA1); aB1 = MFMA(ax[3], wi1[3], aB1);
            }
            // prefetch x[t+2]
            if (t + 2 <= T_STEPS - 1) {
                #pragma unroll
                for (int ks = 0; ks < 4; ++ks) {
                    const float* xp = x + (size_t)(t + 2) * BATCH * IN
                                    + (size_t)(b0 + col) * IN + ks * 32 + quad * 8;
                    xf[2 * ks]     = *(const float4*)xp;
                    xf[2 * ks + 1] = *(const float4*)(xp + 4);
                }
            }
        }
    }

    // ---- final h, c ----
    if (col < 8) {
        #pragma unroll
        for (int r = 0; r < 4; ++r) {
            int row = b0 + quad * 4 + r;
            out[(size_t)row * HID + jcol] = hn[r];
            out[(size_t)BATCH * HID + (size_t)row * HID + jcol] = cst[r];
        }
    }
}

extern "C" void kernel_launch(void* const* d_in, const int* in_sizes, int n_in,
                              void* d_out, int out_size, void* d_ws, size_t ws_size,
                              hipStream_t stream) {
    const float* x    = (const float*)d_in[0];
    const float* W_ih = (const float*)d_in[1];
    const float* W_hh = (const float*)d_in[2];
    const float* b_ih = (const float*)d_in[3];
    const float* b_hh = (const float*)d_in[4];
    const float* hx0  = (const float*)d_in[5];
    const float* cx0  = (const float*)d_in[6];
    float* outp = (float*)d_out;

    __bf16* wcat = (__bf16*)((char*)d_ws + WCAT_OFF);
    float*  bias = (float*)((char*)d_ws + BIAS_OFF);
    u32*    hexg = (u32*)((char*)d_ws + HEXG_OFF);

    precast_kernel<<<dim3((NG * KTOT + 255) / 256), dim3(256), 0, stream>>>(
        W_ih, W_hh, b_ih, b_hh, wcat, bias);

    void* args[] = {(void*)&x, (void*)&wcat, (void*)&bias, (void*)&hx0,
                    (void*)&cx0, (void*)&hexg, (void*)&outp};
    hipLaunchCooperativeKernel((const void*)lstm_kernel, dim3(256), dim3(512),
                               args, 0, stream);
}